// Round 3
// baseline (338.125 us; speedup 1.0000x reference)
//
#include <hip/hip_runtime.h>

// Problem constants
#define B_     64
#define HW_    96
#define COUT_  96
#define KK_    75          // CIN*KH*KW
#define KP_    76          // padded K (multiple of 4 for float4 reads)
#define HOUT_  48
#define L_     2304        // 48*48
#define LR_    0.02f
#define DELTA_ -0.4f
#define OUT_ELEMS (B_*COUT_*L_)
#define NCHUNK2 9              // k2 l-chunks per batch (2304/256)
#define NPART  (B_*NCHUNK2)    // 576 partial rows
#define ROW    (COUT_*KK_ + COUT_)   // 7296 floats: 7200 yx + 96 yy
#define YXP    97              // k2 accumulator col stride: bank=(k+o)%32, spread

// top-2 insert with lax.top_k tiebreak (equal values -> lower channel index)
__device__ __forceinline__ void ins2(float v, int o, float& v1, int& o1,
                                     float& v2, int& o2) {
  bool b1 = (v > v1) || (v == v1 && o < o1);
  bool b2 = (v > v2) || (v == v2 && o < o2);
  if (b1)      { v2 = v1; o2 = o1; v1 = v; o1 = o; }
  else if (b2) { v2 = v;  o2 = o; }
}

__device__ __forceinline__ void im2col_load(const float* __restrict__ xb, int l,
                                            float* __restrict__ pre) {
  const int oh = l / HOUT_, ow = l - oh * HOUT_;
  #pragma unroll
  for (int c = 0; c < 3; ++c) {
    #pragma unroll
    for (int i = 0; i < 5; ++i) {
      int ih = oh * 2 + i - 2;
      bool okh = ((unsigned)ih < (unsigned)HW_);
      #pragma unroll
      for (int j = 0; j < 5; ++j) {
        int iw = ow * 2 + j - 2;
        float v = 0.0f;
        if (okh && ((unsigned)iw < (unsigned)HW_)) v = xb[(c * HW_ + ih) * HW_ + iw];
        pre[c * 25 + i * 5 + j] = v;
      }
    }
  }
  pre[KK_] = 0.0f;
}

// Kernel 1: conv forward + tot + per-position top-2.
// grid (36, 64), block 256. Block = 64 positions x 96 channels.
// Register tile: 4 pos x 6 ch per thread; pre tile shared in LDS (4.8x fewer
// ds_reads than 1-pos-per-thread). lane = ch_slot*16 + pos_slot; a thread's
// positions are pos_slot + 16p so 16 consecutive lanes store 64B runs of out.
__global__ __launch_bounds__(256, 3) void k1_conv(
    const float* __restrict__ x, const float* __restrict__ w,
    float* __restrict__ out, float4* __restrict__ top2)
{
  __shared__ __align__(16) float Ws[COUT_ * KP_];    // 29.2 KB
  __shared__ __align__(16) float preS[64 * KP_];     // 19.5 KB
  __shared__ float4 mrgW[4][64];                     //  4.0 KB
  const int tid = threadIdx.x;
  const int b = blockIdx.y;
  const int blockl = blockIdx.x * 64;

  // stage weights (pad k=75 with 0)
  for (int idx = tid; idx < COUT_ * KP_; idx += 256) {
    int o = idx / KP_, k = idx - o * KP_;
    Ws[idx] = (k < KK_) ? w[o * KK_ + k] : 0.0f;
  }
  // stage pre tile cooperatively: pos = tid>>2, k = (tid&3) + 4*it
  {
    const float* xb = x + (size_t)b * (3 * HW_ * HW_);
    const int pos = tid >> 2;
    const int kb  = tid & 3;
    const int l = blockl + pos;
    const int oh = l / HOUT_, ow = l - oh * HOUT_;
    #pragma unroll
    for (int it = 0; it < 19; ++it) {
      int k = kb + 4 * it;
      float v = 0.0f;
      if (k < KK_) {
        int c = k / 25, r = k - 25 * c;
        int ki = r / 5, kj = r - 5 * ki;
        int ih = 2 * oh + ki - 2;
        int iw = 2 * ow + kj - 2;
        if ((unsigned)ih < (unsigned)HW_ && (unsigned)iw < (unsigned)HW_)
          v = xb[(c * HW_ + ih) * HW_ + iw];
      }
      preS[pos * KP_ + k] = v;
    }
  }
  __syncthreads();

  const int lane = tid & 63, wave = tid >> 6;
  const int pos_slot = lane & 15;
  const int ch_group = wave * 4 + (lane >> 4);   // 0..15, 6 channels each
  const float* wbase = Ws + (size_t)(ch_group * 6) * KP_;
  const float* pbase = preS + pos_slot * KP_;

  float accO[4][6], accT[4][6];
  #pragma unroll
  for (int p = 0; p < 4; ++p)
    #pragma unroll
    for (int cc = 0; cc < 6; ++cc) { accO[p][cc] = 0.f; accT[p][cc] = 0.f; }

  #pragma unroll 2
  for (int kk = 0; kk < KP_ / 4; ++kk) {
    float4 pv[4];
    #pragma unroll
    for (int p = 0; p < 4; ++p)
      pv[p] = *(const float4*)(pbase + p * (16 * KP_) + 4 * kk);
    #pragma unroll
    for (int cc = 0; cc < 6; ++cc) {
      float4 wv = *(const float4*)(wbase + cc * KP_ + 4 * kk);
      float wpx = wv.x * fabsf(wv.x), wpy = wv.y * fabsf(wv.y);
      float wpz = wv.z * fabsf(wv.z), wpw = wv.w * fabsf(wv.w);
      #pragma unroll
      for (int p = 0; p < 4; ++p) {
        accO[p][cc] = fmaf(wv.w, pv[p].w, fmaf(wv.z, pv[p].z,
                      fmaf(wv.y, pv[p].y, fmaf(wv.x, pv[p].x, accO[p][cc]))));
        accT[p][cc] = fmaf(wpw, pv[p].w, fmaf(wpz, pv[p].z,
                      fmaf(wpy, pv[p].y, fmaf(wpx, pv[p].x, accT[p][cc]))));
      }
    }
  }

  // store conv out: 16-lane coalesced 64B runs
  float* outp = out + ((size_t)b * COUT_ + ch_group * 6) * L_ + blockl + pos_slot;
  #pragma unroll
  for (int cc = 0; cc < 6; ++cc)
    #pragma unroll
    for (int p = 0; p < 4; ++p)
      outp[(size_t)cc * L_ + p * 16] = accO[p][cc];

  // per-thread top2 over 6 channels, then in-wave butterfly (xor 16, 32)
  float tv1[4], tv2[4]; int to1[4], to2[4];
  #pragma unroll
  for (int p = 0; p < 4; ++p) {
    tv1[p] = -3.0e38f; tv2[p] = -3.0e38f; to1[p] = 0x7fffffff; to2[p] = 0x7fffffff;
    #pragma unroll
    for (int cc = 0; cc < 6; ++cc)
      ins2(accT[p][cc], ch_group * 6 + cc, tv1[p], to1[p], tv2[p], to2[p]);
  }
  #pragma unroll
  for (int st = 0; st < 2; ++st) {
    const int d = (st == 0) ? 16 : 32;
    #pragma unroll
    for (int p = 0; p < 4; ++p) {
      float bv1 = __shfl_xor(tv1[p], d, 64);
      int   bo1 = __shfl_xor(to1[p], d, 64);
      float bv2 = __shfl_xor(tv2[p], d, 64);
      int   bo2 = __shfl_xor(to2[p], d, 64);
      ins2(bv1, bo1, tv1[p], to1[p], tv2[p], to2[p]);
      ins2(bv2, bo2, tv1[p], to1[p], tv2[p], to2[p]);
    }
  }
  if ((lane >> 4) == 0) {
    #pragma unroll
    for (int p = 0; p < 4; ++p)
      mrgW[wave][pos_slot + 16 * p] =
          make_float4(tv1[p], __int_as_float(to1[p]),
                      tv2[p], __int_as_float(to2[p]));
  }
  __syncthreads();
  if (tid < 64) {   // cross-wave merge, one lane per position
    float4 m0 = mrgW[0][tid];
    float V1 = m0.x; int O1 = __float_as_int(m0.y);
    float V2 = m0.z; int O2 = __float_as_int(m0.w);
    #pragma unroll
    for (int q = 1; q < 4; ++q) {
      float4 m = mrgW[q][tid];
      ins2(m.x, __float_as_int(m.y), V1, O1, V2, O2);
      ins2(m.z, __float_as_int(m.w), V1, O1, V2, O2);
    }
    top2[(size_t)b * L_ + blockl + tid] =
        make_float4(V1, __int_as_float(O1), V2, __int_as_float(O2));
  }
}

// Kernel 2: sparse Hebbian scatter with [k][97]-transposed LDS accumulator.
// Lockstep-k scatter addresses: bank = (97k+o)%32 = (k+o)%32 -> spread by o;
// same-address RMW only for duplicate-o lanes (~3-way), vs full-row pileup before.
__global__ __launch_bounds__(256) void k2_scatter(
    const float* __restrict__ x, const float4* __restrict__ top2,
    float* __restrict__ part)
{
  __shared__ float yxT[KK_ * YXP];   // 29.1 KB, [k][97] cols = channels
  __shared__ float yy[COUT_];
  const int tid = threadIdx.x;
  for (int i = tid; i < KK_ * YXP; i += 256) yxT[i] = 0.0f;
  for (int i = tid; i < COUT_; i += 256) yy[i] = 0.0f;
  __syncthreads();

  const int b = blockIdx.y;
  const int l = blockIdx.x * 256 + tid;
  float pre[KP_];
  im2col_load(x + (size_t)b * (3 * HW_ * HW_), l, pre);
  float4 t2 = top2[(size_t)b * L_ + l];
  const int o1 = __float_as_int(t2.y), o2 = __float_as_int(t2.w);
  atomicAdd(&yy[o1], t2.x);
  atomicAdd(&yy[o2], DELTA_ * t2.z);
  #pragma unroll
  for (int k = 0; k < KK_; ++k) {
    atomicAdd(&yxT[k * YXP + o1], pre[k]);
    atomicAdd(&yxT[k * YXP + o2], DELTA_ * pre[k]);
  }
  __syncthreads();

  float* prow = part + (size_t)(b * NCHUNK2 + blockIdx.x) * ROW;
  for (int i = tid; i < COUT_ * KK_; i += 256) {
    int o = i / KK_, k = i - o * KK_;
    prow[i] = yxT[k * YXP + o];
  }
  for (int i = tid; i < COUT_; i += 256) prow[COUT_ * KK_ + i] = yy[i];
}

// Kernel 3: reduce 576 partial rows -> finals[7296].
// grid 114 x 256: block owns 64 elements, 4-way split over the p dimension.
__global__ __launch_bounds__(256) void k3_reduce(
    const float* __restrict__ part, float* __restrict__ finals)
{
  __shared__ float red[4][64];
  const int e = blockIdx.x * 64 + (threadIdx.x & 63);
  const int seg = threadIdx.x >> 6;
  float s = 0.0f;
  for (int p = seg * (NPART / 4); p < (seg + 1) * (NPART / 4); ++p)
    s += part[(size_t)p * ROW + e];
  red[seg][threadIdx.x & 63] = s;
  __syncthreads();
  if (seg == 0) {
    int ll = threadIdx.x & 63;
    finals[e] = (red[0][ll] + red[1][ll]) + (red[2][ll] + red[3][ll]);
  }
}

// Kernel 4: ds = yx - yy*W; nc = max|ds|; new_W = W + LR*ds/nc.
// (the reference's 1/L cancels inside ds/nc)
__global__ __launch_bounds__(256) void k4_finalize(
    const float* __restrict__ w, const float* __restrict__ finals,
    float* __restrict__ outw)
{
  __shared__ float dsS[COUT_ * KK_];
  __shared__ float wmax[4];
  __shared__ float ncS;
  const int tid = threadIdx.x;
  float m = 0.0f;
  for (int i = tid; i < COUT_ * KK_; i += 256) {
    int o = i / KK_;
    float d = finals[i] - finals[COUT_ * KK_ + o] * w[i];
    dsS[i] = d;
    m = fmaxf(m, fabsf(d));
  }
  #pragma unroll
  for (int s = 32; s > 0; s >>= 1) m = fmaxf(m, __shfl_xor(m, s, 64));
  if ((tid & 63) == 0) wmax[tid >> 6] = m;
  __syncthreads();
  if (tid == 0) {
    float n = fmaxf(fmaxf(wmax[0], wmax[1]), fmaxf(wmax[2], wmax[3]));
    ncS = fmaxf(n, 1e-30f);
  }
  __syncthreads();
  const float scale = LR_ / ncS;
  for (int i = tid; i < COUT_ * KK_; i += 256) {
    outw[i] = w[i] + scale * dsS[i];
  }
}

extern "C" void kernel_launch(void* const* d_in, const int* in_sizes, int n_in,
                              void* d_out, int out_size, void* d_ws, size_t ws_size,
                              hipStream_t stream) {
  (void)in_sizes; (void)n_in; (void)out_size; (void)ws_size;
  const float* x = (const float*)d_in[0];   // [64,3,96,96]
  const float* w = (const float*)d_in[1];   // [96,3,5,5]
  float* out  = (float*)d_out;              // conv out [64,96,48,48]
  float* outw = out + OUT_ELEMS;            // new_weight [96,75]

  float4* top2  = (float4*)d_ws;                       // [64*2304] tuples
  float*  part  = (float*)d_ws + (size_t)4 * B_ * L_;  // [576][7296]
  float*  finals = part + (size_t)NPART * ROW;         // [7296]

  k1_conv   <<<dim3(L_ / 64, B_), 256, 0, stream>>>(x, w, out, top2);
  k2_scatter<<<dim3(NCHUNK2, B_), 256, 0, stream>>>(x, top2, part);
  k3_reduce <<<dim3(ROW / 64), 256, 0, stream>>>(part, finals);
  k4_finalize<<<dim3(1), 256, 0, stream>>>(w, finals, outw);
}

// Round 4
// 312.113 us; speedup vs baseline: 1.0833x; 1.0833x over previous
//
#include <hip/hip_runtime.h>

// Problem constants
#define B_     64
#define HW_    96
#define COUT_  96
#define KK_    75          // CIN*KH*KW
#define KP_    76          // padded K for fp32 im2col (k2)
#define KPAD   96          // padded K for MFMA (3 x 32)
#define HOUT_  48
#define L_     2304        // 48*48
#define LR_    0.02f
#define DELTA_ -0.4f
#define OUT_ELEMS (B_*COUT_*L_)
#define NCHUNK2 9              // k2 l-chunks per batch
#define NPART  (B_*NCHUNK2)    // 576 partial rows
#define ROW    (COUT_*KK_ + COUT_)   // 7296 floats: 7200 yx + 96 yy
#define YXP    97              // k2 accumulator col stride

typedef __attribute__((ext_vector_type(8))) short short8v;   // 8 bf16
typedef __attribute__((ext_vector_type(4))) float float4v;   // 4 f32 acc

__device__ __forceinline__ unsigned short f2bf(float f) {  // RNE f32->bf16
  unsigned u = __float_as_uint(f);
  u += 0x7fff + ((u >> 16) & 1);
  return (unsigned short)(u >> 16);
}

// top-2 insert with lax.top_k tiebreak (equal values -> lower channel index)
__device__ __forceinline__ void ins2(float v, int o, float& v1, int& o1,
                                     float& v2, int& o2) {
  bool b1 = (v > v1) || (v == v1 && o < o1);
  bool b2 = (v > v2) || (v == v2 && o < o2);
  if (b1)      { v2 = v1; o2 = o1; v1 = v; o1 = o; }
  else if (b2) { v2 = v;  o2 = o; }
}

__device__ __forceinline__ void im2col_load(const float* __restrict__ xb, int l,
                                            float* __restrict__ pre) {
  const int oh = l / HOUT_, ow = l - oh * HOUT_;
  #pragma unroll
  for (int c = 0; c < 3; ++c) {
    #pragma unroll
    for (int i = 0; i < 5; ++i) {
      int ih = oh * 2 + i - 2;
      bool okh = ((unsigned)ih < (unsigned)HW_);
      #pragma unroll
      for (int j = 0; j < 5; ++j) {
        int iw = ow * 2 + j - 2;
        float v = 0.0f;
        if (okh && ((unsigned)iw < (unsigned)HW_)) v = xb[(c * HW_ + ih) * HW_ + iw];
        pre[c * 25 + i * 5 + j] = v;
      }
    }
  }
  pre[KK_] = 0.0f;
}

// Kernel 0: build stacked bf16 A-matrix [192][96]: rows 0..95 = W, 96..191 = W*|W|.
__global__ __launch_bounds__(256) void k0_prep(const float* __restrict__ w,
                                               unsigned short* __restrict__ wbf) {
  int i = blockIdx.x * 256 + threadIdx.x;
  if (i >= 192 * KPAD) return;
  int row = i / KPAD, k = i - row * KPAD;
  float v = 0.0f;
  if (k < KK_) {
    float ww = w[(row % COUT_) * KK_ + k];
    v = (row < COUT_) ? ww : ww * fabsf(ww);   // sign(w)|w|^2, p=3
  }
  wbf[i] = f2bf(v);
}

// Kernel 1: MFMA conv forward + tot + per-position top-2.
// grid (36, 64), block 256 = 4 waves. Block = 64 positions x 192 stacked rows.
// Wave q owns rows [48q, 48q+48): waves 0-1 = W (store out), 2-3 = Wp (top-2).
// A fragments in registers (wbf is L1-resident, reused by every block).
// PRE tile [64 pos][128 bf16] in LDS, XOR-swizzled (dword ^= (pos&7)<<2) so
// B-fragment ds_read_b128 (16 rows @ 256B stride) is conflict-free.
__global__ __launch_bounds__(256, 3) void k1_mfma(
    const float* __restrict__ x, const unsigned short* __restrict__ wbf,
    float* __restrict__ out, float4* __restrict__ top2)
{
  __shared__ __align__(16) unsigned short preS[64 * 128];  // 16 KB
  __shared__ float4 mrg[2][64];
  const int tid = threadIdx.x;
  const int b = blockIdx.y;
  const int blockl = blockIdx.x * 64;
  const float* xb = x + (size_t)b * (3 * HW_ * HW_);

  // stage PRE tile in bf16: thread covers pos = tid&63, k in [24*(tid>>6), +24)
  {
    const int pos = tid & 63;
    const int kb  = (tid >> 6) * 24;
    const int l = blockl + pos;
    const int oh = l / HOUT_, ow = l - oh * HOUT_;
    unsigned* dst = (unsigned*)preS + pos * 64;
    const int sw = (pos & 7) << 2;               // dword swizzle
    #pragma unroll
    for (int j = 0; j < 12; ++j) {
      int k0 = kb + 2 * j;
      float v0 = 0.f, v1 = 0.f;
      if (k0 < KK_) {
        int c = k0 / 25, r = k0 - 25 * c, ki = r / 5, kj = r - 5 * ki;
        int ih = 2 * oh + ki - 2, iw = 2 * ow + kj - 2;
        if ((unsigned)ih < (unsigned)HW_ && (unsigned)iw < (unsigned)HW_)
          v0 = xb[(c * HW_ + ih) * HW_ + iw];
      }
      if (k0 + 1 < KK_) {
        int k1e = k0 + 1;
        int c = k1e / 25, r = k1e - 25 * c, ki = r / 5, kj = r - 5 * ki;
        int ih = 2 * oh + ki - 2, iw = 2 * ow + kj - 2;
        if ((unsigned)ih < (unsigned)HW_ && (unsigned)iw < (unsigned)HW_)
          v1 = xb[(c * HW_ + ih) * HW_ + iw];
      }
      unsigned word = (unsigned)f2bf(v0) | ((unsigned)f2bf(v1) << 16);
      dst[((kb >> 1) + j) ^ sw] = word;          // k>=75 lanes write zeros (pad)
    }
  }

  const int lane = tid & 63, wq = tid >> 6;
  const int col = lane & 15, g = lane >> 4;

  // A fragments: A[m][k], m = lane&15, k = 8*(lane>>4)+j  (16B per lane per frag)
  short8v afr[3][3];
  #pragma unroll
  for (int mt = 0; mt < 3; ++mt)
    #pragma unroll
    for (int kt = 0; kt < 3; ++kt)
      afr[mt][kt] = *(const short8v*)(
          wbf + ((wq * 48 + mt * 16 + col) * KPAD + kt * 32 + g * 8));

  float4v acc[3][4];
  #pragma unroll
  for (int mt = 0; mt < 3; ++mt)
    #pragma unroll
    for (int nt = 0; nt < 4; ++nt) acc[mt][nt] = (float4v)(0.0f);

  __syncthreads();

  // MFMA main: B[k][n], n = lane&15 (row of preS), k = 8*(lane>>4)+j
  #pragma unroll
  for (int kt = 0; kt < 3; ++kt) {
    #pragma unroll
    for (int nt = 0; nt < 4; ++nt) {
      const int n = nt * 16 + col;
      const int boff = n * 256 + ((kt * 64 + g * 16) ^ ((n & 7) << 4));
      short8v bfr = *(const short8v*)((const char*)preS + boff);
      #pragma unroll
      for (int mt = 0; mt < 3; ++mt)
        acc[mt][nt] = __builtin_amdgcn_mfma_f32_16x16x32_bf16(
            afr[mt][kt], bfr, acc[mt][nt], 0, 0, 0);
    }
  }

  if (wq < 2) {
    // conv out store: C/D layout col=lane&15, row=(lane>>4)*4+reg (verified m89)
    #pragma unroll
    for (int mt = 0; mt < 3; ++mt) {
      #pragma unroll
      for (int r = 0; r < 4; ++r) {
        const int ch = wq * 48 + mt * 16 + g * 4 + r;
        float* op = out + ((size_t)b * COUT_ + ch) * L_ + blockl + col;
        #pragma unroll
        for (int nt = 0; nt < 4; ++nt)
          op[nt * 16] = acc[mt][nt][r];
      }
    }
  } else {
    // top-2 over this wave's 48 tot-channels, per position
    float v1[4], v2[4]; int o1[4], o2[4];
    #pragma unroll
    for (int nt = 0; nt < 4; ++nt) {
      v1[nt] = -3.0e38f; v2[nt] = -3.0e38f;
      o1[nt] = 0x7fffffff; o2[nt] = 0x7fffffff;
      #pragma unroll
      for (int mt = 0; mt < 3; ++mt)
        #pragma unroll
        for (int r = 0; r < 4; ++r)
          ins2(acc[mt][nt][r], (wq - 2) * 48 + mt * 16 + g * 4 + r,
               v1[nt], o1[nt], v2[nt], o2[nt]);
    }
    #pragma unroll
    for (int st = 0; st < 2; ++st) {   // butterfly over the 4 row-groups
      const int d = (st == 0) ? 16 : 32;
      #pragma unroll
      for (int nt = 0; nt < 4; ++nt) {
        float bv1 = __shfl_xor(v1[nt], d, 64);
        int   bo1 = __shfl_xor(o1[nt], d, 64);
        float bv2 = __shfl_xor(v2[nt], d, 64);
        int   bo2 = __shfl_xor(o2[nt], d, 64);
        ins2(bv1, bo1, v1[nt], o1[nt], v2[nt], o2[nt]);
        ins2(bv2, bo2, v1[nt], o1[nt], v2[nt], o2[nt]);
      }
    }
    if (g == 0) {
      #pragma unroll
      for (int nt = 0; nt < 4; ++nt)
        mrg[wq - 2][nt * 16 + col] =
            make_float4(v1[nt], __int_as_float(o1[nt]),
                        v2[nt], __int_as_float(o2[nt]));
    }
  }
  __syncthreads();
  if (tid < 64) {   // merge the two channel halves, write global top2
    float4 m0 = mrg[0][tid], m1 = mrg[1][tid];
    float V1 = m0.x; int O1 = __float_as_int(m0.y);
    float V2 = m0.z; int O2 = __float_as_int(m0.w);
    ins2(m1.x, __float_as_int(m1.y), V1, O1, V2, O2);
    ins2(m1.z, __float_as_int(m1.w), V1, O1, V2, O2);
    top2[(size_t)b * L_ + blockl + tid] =
        make_float4(V1, __int_as_float(O1), V2, __int_as_float(O2));
  }
}

// Kernel 2: sparse Hebbian scatter. grid (9,64), block 256.
// STRIDE-9 lane->position map: lanes in a wave are 9 positions apart, so their
// 5x5/stride-2 patches are disjoint -> top-1 winners decorrelated -> no
// same-address ds_add_f32 pileup (the round-2/3 157us cost).
__global__ __launch_bounds__(256) void k2_scatter(
    const float* __restrict__ x, const float4* __restrict__ top2,
    float* __restrict__ part)
{
  __shared__ float yxT[KK_ * YXP];   // [k][97], bank=(k+o)%32
  __shared__ float yy[COUT_];
  const int tid = threadIdx.x;
  for (int i = tid; i < KK_ * YXP; i += 256) yxT[i] = 0.0f;
  for (int i = tid; i < COUT_; i += 256) yy[i] = 0.0f;
  __syncthreads();

  const int b = blockIdx.y;
  const int l = blockIdx.x + NCHUNK2 * tid;    // stride-9 decorrelation
  float pre[KP_];
  im2col_load(x + (size_t)b * (3 * HW_ * HW_), l, pre);
  float4 t2 = top2[(size_t)b * L_ + l];
  const int o1 = __float_as_int(t2.y), o2 = __float_as_int(t2.w);
  atomicAdd(&yy[o1], t2.x);
  atomicAdd(&yy[o2], DELTA_ * t2.z);
  #pragma unroll
  for (int k = 0; k < KK_; ++k) {
    atomicAdd(&yxT[k * YXP + o1], pre[k]);
    atomicAdd(&yxT[k * YXP + o2], DELTA_ * pre[k]);
  }
  __syncthreads();

  float* prow = part + (size_t)(b * NCHUNK2 + blockIdx.x) * ROW;
  for (int i = tid; i < COUT_ * KK_; i += 256) {
    int o = i / KK_, k = i - o * KK_;
    prow[i] = yxT[k * YXP + o];
  }
  for (int i = tid; i < COUT_; i += 256) prow[COUT_ * KK_ + i] = yy[i];
}

// Kernel 3: reduce 576 partial rows -> finals[7296]. 114 blocks, 4-way p-split.
__global__ __launch_bounds__(256) void k3_reduce(
    const float* __restrict__ part, float* __restrict__ finals)
{
  __shared__ float red[4][64];
  const int e = blockIdx.x * 64 + (threadIdx.x & 63);
  const int seg = threadIdx.x >> 6;
  float s = 0.0f;
  for (int p = seg * (NPART / 4); p < (seg + 1) * (NPART / 4); ++p)
    s += part[(size_t)p * ROW + e];
  red[seg][threadIdx.x & 63] = s;
  __syncthreads();
  if (seg == 0) {
    int ll = threadIdx.x & 63;
    finals[e] = (red[0][ll] + red[1][ll]) + (red[2][ll] + red[3][ll]);
  }
}

// Kernel 4: ds = yx - yy*W; nc = max|ds|; new_W = W + LR*ds/nc.
__global__ __launch_bounds__(256) void k4_finalize(
    const float* __restrict__ w, const float* __restrict__ finals,
    float* __restrict__ outw)
{
  __shared__ float dsS[COUT_ * KK_];
  __shared__ float wmax[4];
  __shared__ float ncS;
  const int tid = threadIdx.x;
  float m = 0.0f;
  for (int i = tid; i < COUT_ * KK_; i += 256) {
    int o = i / KK_;
    float d = finals[i] - finals[COUT_ * KK_ + o] * w[i];
    dsS[i] = d;
    m = fmaxf(m, fabsf(d));
  }
  #pragma unroll
  for (int s = 32; s > 0; s >>= 1) m = fmaxf(m, __shfl_xor(m, s, 64));
  if ((tid & 63) == 0) wmax[tid >> 6] = m;
  __syncthreads();
  if (tid == 0) {
    float n = fmaxf(fmaxf(wmax[0], wmax[1]), fmaxf(wmax[2], wmax[3]));
    ncS = fmaxf(n, 1e-30f);
  }
  __syncthreads();
  const float scale = LR_ / ncS;
  for (int i = tid; i < COUT_ * KK_; i += 256) {
    outw[i] = w[i] + scale * dsS[i];
  }
}

extern "C" void kernel_launch(void* const* d_in, const int* in_sizes, int n_in,
                              void* d_out, int out_size, void* d_ws, size_t ws_size,
                              hipStream_t stream) {
  (void)in_sizes; (void)n_in; (void)out_size; (void)ws_size;
  const float* x = (const float*)d_in[0];   // [64,3,96,96]
  const float* w = (const float*)d_in[1];   // [96,3,5,5]
  float* out  = (float*)d_out;              // conv out [64,96,48,48]
  float* outw = out + OUT_ELEMS;            // new_weight [96,75]

  unsigned short* wbf = (unsigned short*)d_ws;               // [192*96] bf16
  float4* top2 = (float4*)((char*)d_ws + 192 * KPAD * 2);    // [64*2304]
  float*  part = (float*)((char*)d_ws + 192 * KPAD * 2
                          + (size_t)B_ * L_ * sizeof(float4)); // [576][7296]
  float*  finals = part + (size_t)NPART * ROW;               // [7296]

  k0_prep   <<<dim3((192 * KPAD + 255) / 256), 256, 0, stream>>>(w, wbf);
  k1_mfma   <<<dim3(L_ / 64, B_), 256, 0, stream>>>(x, wbf, out, top2);
  k2_scatter<<<dim3(NCHUNK2, B_), 256, 0, stream>>>(x, top2, part);
  k3_reduce <<<dim3(ROW / 64), 256, 0, stream>>>(part, finals);
  k4_finalize<<<dim3(1), 256, 0, stream>>>(w, finals, outw);
}

// Round 5
// 165.978 us; speedup vs baseline: 2.0372x; 1.8804x over previous
//
#include <hip/hip_runtime.h>

// Problem constants
#define B_     64
#define HW_    96
#define COUT_  96
#define KK_    75          // CIN*KH*KW
#define KP_    76          // padded K for fp32 im2col
#define KPAD   96          // padded K for k1 MFMA (3 x 32)
#define HOUT_  48
#define L_     2304        // 48*48
#define LR_    0.02f
#define DELTA_ -0.4f
#define OUT_ELEMS (B_*COUT_*L_)
#define CL2    256                  // k2 l-chunk size
#define CPB2   3                    // l-chunks per k2 block
#define NPART2 (B_*3)               // 192 partial rows
#define PROW2  (COUT_*96 + COUT_)   // 9312 floats: yx[96][96] + yy[96]
#define NFIN   (COUT_*KK_ + COUT_)  // 7296 finals

typedef __attribute__((ext_vector_type(8))) short short8v;   // 8 bf16
typedef __attribute__((ext_vector_type(4))) float float4v;   // 4 f32 acc

__device__ __forceinline__ unsigned short f2bf(float f) {  // RNE f32->bf16
  unsigned u = __float_as_uint(f);
  u += 0x7fff + ((u >> 16) & 1);
  return (unsigned short)(u >> 16);
}

// top-2 insert with lax.top_k tiebreak (equal values -> lower channel index)
__device__ __forceinline__ void ins2(float v, int o, float& v1, int& o1,
                                     float& v2, int& o2) {
  bool b1 = (v > v1) || (v == v1 && o < o1);
  bool b2 = (v > v2) || (v == v2 && o < o2);
  if (b1)      { v2 = v1; o2 = o1; v1 = v; o1 = o; }
  else if (b2) { v2 = v;  o2 = o; }
}

__device__ __forceinline__ void im2col_load(const float* __restrict__ xb, int l,
                                            float* __restrict__ pre) {
  const int oh = l / HOUT_, ow = l - oh * HOUT_;
  #pragma unroll
  for (int c = 0; c < 3; ++c) {
    #pragma unroll
    for (int i = 0; i < 5; ++i) {
      int ih = oh * 2 + i - 2;
      bool okh = ((unsigned)ih < (unsigned)HW_);
      #pragma unroll
      for (int j = 0; j < 5; ++j) {
        int iw = ow * 2 + j - 2;
        float v = 0.0f;
        if (okh && ((unsigned)iw < (unsigned)HW_)) v = xb[(c * HW_ + ih) * HW_ + iw];
        pre[c * 25 + i * 5 + j] = v;
      }
    }
  }
  pre[KK_] = 0.0f;
}

// Kernel 0: build stacked bf16 A-matrix [192][96]: rows 0..95 = W, 96..191 = W*|W|.
__global__ __launch_bounds__(256) void k0_prep(const float* __restrict__ w,
                                               unsigned short* __restrict__ wbf) {
  int i = blockIdx.x * 256 + threadIdx.x;
  if (i >= 192 * KPAD) return;
  int row = i / KPAD, k = i - row * KPAD;
  float v = 0.0f;
  if (k < KK_) {
    float ww = w[(row % COUT_) * KK_ + k];
    v = (row < COUT_) ? ww : ww * fabsf(ww);   // sign(w)|w|^2, p=3
  }
  wbf[i] = f2bf(v);
}

// Kernel 1: MFMA conv forward + tot + per-position top-2. (structure = round 4)
__global__ __launch_bounds__(256, 4) void k1_mfma(
    const float* __restrict__ x, const unsigned short* __restrict__ wbf,
    float* __restrict__ out, float4* __restrict__ top2)
{
  __shared__ __align__(16) unsigned short preS[64 * 128];  // 16 KB
  __shared__ float4 mrg[2][64];
  const int tid = threadIdx.x;
  const int b = blockIdx.y;
  const int blockl = blockIdx.x * 64;
  const float* xb = x + (size_t)b * (3 * HW_ * HW_);

  {
    const int pos = tid & 63;
    const int kb  = (tid >> 6) * 24;
    const int l = blockl + pos;
    const int oh = l / HOUT_, ow = l - oh * HOUT_;
    unsigned* dst = (unsigned*)preS + pos * 64;
    const int sw = (pos & 7) << 2;               // dword swizzle
    #pragma unroll
    for (int j = 0; j < 12; ++j) {
      int k0 = kb + 2 * j;
      float v0 = 0.f, v1 = 0.f;
      if (k0 < KK_) {
        int c = k0 / 25, r = k0 - 25 * c, ki = r / 5, kj = r - 5 * ki;
        int ih = 2 * oh + ki - 2, iw = 2 * ow + kj - 2;
        if ((unsigned)ih < (unsigned)HW_ && (unsigned)iw < (unsigned)HW_)
          v0 = xb[(c * HW_ + ih) * HW_ + iw];
      }
      if (k0 + 1 < KK_) {
        int k1e = k0 + 1;
        int c = k1e / 25, r = k1e - 25 * c, ki = r / 5, kj = r - 5 * ki;
        int ih = 2 * oh + ki - 2, iw = 2 * ow + kj - 2;
        if ((unsigned)ih < (unsigned)HW_ && (unsigned)iw < (unsigned)HW_)
          v1 = xb[(c * HW_ + ih) * HW_ + iw];
      }
      unsigned word = (unsigned)f2bf(v0) | ((unsigned)f2bf(v1) << 16);
      dst[((kb >> 1) + j) ^ sw] = word;
    }
  }

  const int lane = tid & 63, wq = tid >> 6;
  const int col = lane & 15, g = lane >> 4;

  short8v afr[3][3];
  #pragma unroll
  for (int mt = 0; mt < 3; ++mt)
    #pragma unroll
    for (int kt = 0; kt < 3; ++kt)
      afr[mt][kt] = *(const short8v*)(
          wbf + ((wq * 48 + mt * 16 + col) * KPAD + kt * 32 + g * 8));

  float4v acc[3][4];
  #pragma unroll
  for (int mt = 0; mt < 3; ++mt)
    #pragma unroll
    for (int nt = 0; nt < 4; ++nt) acc[mt][nt] = (float4v)(0.0f);

  __syncthreads();

  #pragma unroll
  for (int kt = 0; kt < 3; ++kt) {
    #pragma unroll
    for (int nt = 0; nt < 4; ++nt) {
      const int n = nt * 16 + col;
      const int boff = n * 256 + ((kt * 64 + g * 16) ^ ((n & 7) << 4));
      short8v bfr = *(const short8v*)((const char*)preS + boff);
      #pragma unroll
      for (int mt = 0; mt < 3; ++mt)
        acc[mt][nt] = __builtin_amdgcn_mfma_f32_16x16x32_bf16(
            afr[mt][kt], bfr, acc[mt][nt], 0, 0, 0);
    }
  }

  if (wq < 2) {
    #pragma unroll
    for (int mt = 0; mt < 3; ++mt) {
      #pragma unroll
      for (int r = 0; r < 4; ++r) {
        const int ch = wq * 48 + mt * 16 + g * 4 + r;
        float* op = out + ((size_t)b * COUT_ + ch) * L_ + blockl + col;
        #pragma unroll
        for (int nt = 0; nt < 4; ++nt)
          op[nt * 16] = acc[mt][nt][r];
      }
    }
  } else {
    float v1[4], v2[4]; int o1[4], o2[4];
    #pragma unroll
    for (int nt = 0; nt < 4; ++nt) {
      v1[nt] = -3.0e38f; v2[nt] = -3.0e38f;
      o1[nt] = 0x7fffffff; o2[nt] = 0x7fffffff;
      #pragma unroll
      for (int mt = 0; mt < 3; ++mt)
        #pragma unroll
        for (int r = 0; r < 4; ++r)
          ins2(acc[mt][nt][r], (wq - 2) * 48 + mt * 16 + g * 4 + r,
               v1[nt], o1[nt], v2[nt], o2[nt]);
    }
    #pragma unroll
    for (int st = 0; st < 2; ++st) {
      const int d = (st == 0) ? 16 : 32;
      #pragma unroll
      for (int nt = 0; nt < 4; ++nt) {
        float bv1 = __shfl_xor(v1[nt], d, 64);
        int   bo1 = __shfl_xor(o1[nt], d, 64);
        float bv2 = __shfl_xor(v2[nt], d, 64);
        int   bo2 = __shfl_xor(o2[nt], d, 64);
        ins2(bv1, bo1, v1[nt], o1[nt], v2[nt], o2[nt]);
        ins2(bv2, bo2, v1[nt], o1[nt], v2[nt], o2[nt]);
      }
    }
    if (g == 0) {
      #pragma unroll
      for (int nt = 0; nt < 4; ++nt)
        mrg[wq - 2][nt * 16 + col] =
            make_float4(v1[nt], __int_as_float(o1[nt]),
                        v2[nt], __int_as_float(o2[nt]));
    }
  }
  __syncthreads();
  if (tid < 64) {
    float4 m0 = mrg[0][tid], m1 = mrg[1][tid];
    float V1 = m0.x; int O1 = __float_as_int(m0.y);
    float V2 = m0.z; int O2 = __float_as_int(m0.w);
    ins2(m1.x, __float_as_int(m1.y), V1, O1, V2, O2);
    ins2(m1.z, __float_as_int(m1.w), V1, O1, V2, O2);
    top2[(size_t)b * L_ + blockl + tid] =
        make_float4(V1, __int_as_float(O1), V2, __int_as_float(O2));
  }
}

// Kernel 2: yx/yy via MFMA — NO per-k atomics.
// grid (3, 64), block 256, ~96KB LDS. Block processes 3 l-chunks of 256:
// per chunk, build act[96][256] bf16 (2 plain b16 stores per position; (o,pos)
// unique -> no atomics) and preT[96kw][256pos] bf16 (im2col, transposed),
// both with block16 ^= row&7 swizzle (balanced 8-lane/16B-block b128 reads),
// then C[96ch][96kw] += act x preT over K=256 via 36 MFMA tiles x 8 k-steps.
// Only 2 yy LDS-atomics per position remain (0.3% of old atomic count).
__global__ __launch_bounds__(256, 1) void k2_gemm(
    const float* __restrict__ x, const float4* __restrict__ top2,
    float* __restrict__ part)
{
  __shared__ __align__(16) unsigned short actS[COUT_ * CL2];  // 48 KB
  __shared__ __align__(16) unsigned short preT[COUT_ * CL2];  // 48 KB
  __shared__ float yyS[COUT_];
  const int tid = threadIdx.x;
  const int b = blockIdx.y;
  const int pos = tid;
  const float* xb = x + (size_t)b * (3 * HW_ * HW_);

  // one-time zero of both buffers + yy
  {
    float4* a4 = (float4*)actS;
    float4* p4 = (float4*)preT;
    #pragma unroll
    for (int i = 0; i < 12; ++i) {            // 3072 float4 per buffer
      a4[tid + i * 256] = make_float4(0, 0, 0, 0);
      p4[tid + i * 256] = make_float4(0, 0, 0, 0);
    }
    if (tid < COUT_) yyS[tid] = 0.0f;
  }
  __syncthreads();

  const int lane = tid & 63, w = tid >> 6;
  const int col = lane & 15, g = lane >> 4;
  const int mb = (w >> 1) * 48, nb = (w & 1) * 48;   // wave's C quadrant

  float4v acc[3][3];
  #pragma unroll
  for (int mt = 0; mt < 3; ++mt)
    #pragma unroll
    for (int nt = 0; nt < 3; ++nt) acc[mt][nt] = (float4v)(0.0f);

  int prevA = -1, prevB = -1;   // this thread's act writes from previous chunk

  for (int ch = 0; ch < CPB2; ++ch) {
    const int l0 = (blockIdx.x * CPB2 + ch) * CL2;

    // clear this thread's previous-round act entries (pos is thread-local,
    // so clear-then-write has no cross-thread race)
    if (prevA >= 0) {
      *(unsigned short*)((char*)actS + prevA) = 0;
      *(unsigned short*)((char*)actS + prevB) = 0;
    }

    // stage preT (im2col, transposed + swizzled)
    {
      float pre[KP_];
      im2col_load(xb, l0 + pos, pre);
      const int pblk = pos >> 3, plo = (pos & 7) << 1;
      #pragma unroll
      for (int k = 0; k < KK_; ++k) {
        int byteoff = k * 512 + ((pblk ^ (k & 7)) << 4) + plo;
        *(unsigned short*)((char*)preT + byteoff) = f2bf(pre[k]);
      }
      // act scatter + yy accumulation
      float4 t2 = top2[(size_t)b * L_ + l0 + pos];
      int o1 = __float_as_int(t2.y), o2 = __float_as_int(t2.w);
      prevA = o1 * 512 + ((pblk ^ (o1 & 7)) << 4) + plo;
      prevB = o2 * 512 + ((pblk ^ (o2 & 7)) << 4) + plo;
      *(unsigned short*)((char*)actS + prevA) = 0x3F80;        // bf16(1.0)
      *(unsigned short*)((char*)actS + prevB) = f2bf(DELTA_);
      atomicAdd(&yyS[o1], t2.x);
      atomicAdd(&yyS[o2], DELTA_ * t2.z);
    }
    __syncthreads();

    // MFMA: acc[mt][nt] += act-quadrant x preT-quadrant over K=256
    #pragma unroll
    for (int kt = 0; kt < 8; ++kt) {
      short8v a[3], bf[3];
      #pragma unroll
      for (int mt = 0; mt < 3; ++mt) {
        int row = mb + mt * 16 + col;
        a[mt] = *(const short8v*)((char*)actS + row * 512 +
                                  (((kt * 4 + g) ^ (row & 7)) << 4));
      }
      #pragma unroll
      for (int nt = 0; nt < 3; ++nt) {
        int row = nb + nt * 16 + col;
        bf[nt] = *(const short8v*)((char*)preT + row * 512 +
                                   (((kt * 4 + g) ^ (row & 7)) << 4));
      }
      #pragma unroll
      for (int mt = 0; mt < 3; ++mt)
        #pragma unroll
        for (int nt = 0; nt < 3; ++nt)
          acc[mt][nt] = __builtin_amdgcn_mfma_f32_16x16x32_bf16(
              a[mt], bf[nt], acc[mt][nt], 0, 0, 0);
    }
    __syncthreads();   // all reads done before next round's clears/stores
  }

  // write partial: yx[96][96] + yy[96]
  float* prow = part + (size_t)(b * 3 + blockIdx.x) * PROW2;
  #pragma unroll
  for (int mt = 0; mt < 3; ++mt)
    #pragma unroll
    for (int nt = 0; nt < 3; ++nt)
      #pragma unroll
      for (int r = 0; r < 4; ++r) {
        int m = mb + mt * 16 + g * 4 + r;
        int n = nb + nt * 16 + col;
        prow[m * 96 + n] = acc[mt][nt][r];
      }
  if (tid < COUT_) prow[9216 + tid] = yyS[tid];
}

// Kernel 3: reduce 192 partial rows [9312] -> finals[7296] (drops kw pad cols).
__global__ __launch_bounds__(256) void k3_reduce(
    const float* __restrict__ part, float* __restrict__ finals)
{
  __shared__ float red[4][64];
  const int e = blockIdx.x * 64 + (threadIdx.x & 63);
  const int seg = threadIdx.x >> 6;
  float s = 0.0f;
  if (e < PROW2)
    for (int p = seg * (NPART2 / 4); p < (seg + 1) * (NPART2 / 4); ++p)
      s += part[(size_t)p * PROW2 + e];
  red[seg][threadIdx.x & 63] = s;
  __syncthreads();
  if (seg == 0 && e < PROW2) {
    int ll = threadIdx.x & 63;
    float t = (red[0][ll] + red[1][ll]) + (red[2][ll] + red[3][ll]);
    if (e < 9216) {
      int o = e / 96, kw = e - o * 96;
      if (kw < KK_) finals[o * KK_ + kw] = t;
    } else {
      finals[COUT_ * KK_ + (e - 9216)] = t;
    }
  }
}

// Kernel 4: ds = yx - yy*W; nc = max|ds|; new_W = W + LR*ds/nc.
__global__ __launch_bounds__(256) void k4_finalize(
    const float* __restrict__ w, const float* __restrict__ finals,
    float* __restrict__ outw)
{
  __shared__ float dsS[COUT_ * KK_];
  __shared__ float wmax[4];
  __shared__ float ncS;
  const int tid = threadIdx.x;
  float m = 0.0f;
  for (int i = tid; i < COUT_ * KK_; i += 256) {
    int o = i / KK_;
    float d = finals[i] - finals[COUT_ * KK_ + o] * w[i];
    dsS[i] = d;
    m = fmaxf(m, fabsf(d));
  }
  #pragma unroll
  for (int s = 32; s > 0; s >>= 1) m = fmaxf(m, __shfl_xor(m, s, 64));
  if ((tid & 63) == 0) wmax[tid >> 6] = m;
  __syncthreads();
  if (tid == 0) {
    float n = fmaxf(fmaxf(wmax[0], wmax[1]), fmaxf(wmax[2], wmax[3]));
    ncS = fmaxf(n, 1e-30f);
  }
  __syncthreads();
  const float scale = LR_ / ncS;
  for (int i = tid; i < COUT_ * KK_; i += 256) {
    outw[i] = w[i] + scale * dsS[i];
  }
}

extern "C" void kernel_launch(void* const* d_in, const int* in_sizes, int n_in,
                              void* d_out, int out_size, void* d_ws, size_t ws_size,
                              hipStream_t stream) {
  (void)in_sizes; (void)n_in; (void)out_size; (void)ws_size;
  const float* x = (const float*)d_in[0];   // [64,3,96,96]
  const float* w = (const float*)d_in[1];   // [96,3,5,5]
  float* out  = (float*)d_out;              // conv out [64,96,48,48]
  float* outw = out + OUT_ELEMS;            // new_weight [96,75]

  unsigned short* wbf = (unsigned short*)d_ws;               // [192*96] bf16
  float4* top2 = (float4*)((char*)d_ws + 192 * KPAD * 2);    // [64*2304]
  float*  part = (float*)((char*)top2 + (size_t)B_ * L_ * sizeof(float4)); // [192][9312]
  float*  finals = part + (size_t)NPART2 * PROW2;            // [7296]

  k0_prep   <<<dim3((192 * KPAD + 255) / 256), 256, 0, stream>>>(w, wbf);
  k1_mfma   <<<dim3(L_ / 64, B_), 256, 0, stream>>>(x, wbf, out, top2);
  k2_gemm   <<<dim3(3, B_), 256, 0, stream>>>(x, top2, part);
  k3_reduce <<<dim3((PROW2 + 63) / 64), 256, 0, stream>>>(part, finals);
  k4_finalize<<<dim3(1), 256, 0, stream>>>(w, finals, outw);
}